// Round 3
// baseline (722.192 us; speedup 1.0000x reference)
//
#include <hip/hip_runtime.h>

typedef __bf16 bf16;
typedef __bf16 bf16x8 __attribute__((ext_vector_type(8)));
typedef float f32x4 __attribute__((ext_vector_type(4)));

#define HD 768
#define ELTS 6291456   // 8*1024*768

__device__ __forceinline__ void gld_lds16(const bf16* g, bf16* l) {
  __builtin_amdgcn_global_load_lds((const __attribute__((address_space(1))) void*)g,
                                   (__attribute__((address_space(3))) void*)l, 16, 0, 0);
}

__device__ __forceinline__ float rdscalar(const void* p, int f) {
  return f ? (float)((const bf16*)p)[0] : ((const float*)p)[0];
}

__global__ void probe_dtype(const unsigned int* __restrict__ x, int* flag) {
  const int t = threadIdx.x;  // 64 threads
  int bad = 0;
#pragma unroll
  for (int i = 0; i < 4; ++i) {
    unsigned int wd = x[t * 4 + i];
    unsigned int e0 = (wd >> 7) & 0xFF;
    unsigned int e1 = (wd >> 23) & 0xFF;
    bad += (e0 >= 134) + (e1 >= 134);
  }
  unsigned long long m = __ballot(bad > 0);
  if (t == 0) *flag = (m == 0ULL) ? 1 : 0;   // 1 = bf16 inputs
}

struct GemmArgs {
  const void* A[6];
  const void* W[6];
  const void* bias[6];
  const void* s0[6];
  const void* s1[6];
  void* C[6];       // for out_elem_off>0 this is d_out base
  int a_fixed[6];   // 1: A always internal bf16
  int c_fixed[6];   // 1: C always internal bf16; 0: C dtype follows flag
  long long out_elem_off[6];  // element offset applied to C (dtype-aware)
  const int* flag;
};

__global__ __launch_bounds__(256) void gemm_bt(GemmArgs args) {
  const int g = blockIdx.z;
  const int f = *args.flag;
  const bool a_bf = args.a_fixed[g] || f;
  const bool c_bf = args.c_fixed[g] || f;
  const void* __restrict__ A = args.A[g];
  const void* __restrict__ W = args.W[g];
  bf16* Cb = (bf16*)args.C[g] + args.out_elem_off[g];
  float* Cf = (float*)args.C[g] + args.out_elem_off[g];
  float bscale = 1.0f;
  if (args.s0[g]) bscale = rdscalar(args.s0[g], f) + rdscalar(args.s1[g], f);

  const int m0 = blockIdx.x * 128;
  const int n0 = blockIdx.y * 128;
  const int t = threadIdx.x;
  const int lane = t & 63;
  const int w = t >> 6;
  const int wm = (w >> 1) * 64, wn = (w & 1) * 64;

  __shared__ __attribute__((aligned(16))) bf16 As[128 * 32];
  __shared__ __attribute__((aligned(16))) bf16 Bs[128 * 32];

  f32x4 acc[4][4] = {};

  const int c0 = t, c1 = t + 256;
  const int r0 = c0 >> 2, k40 = (c0 & 3) * 8;
  const int r1 = c1 >> 2, k41 = (c1 & 3) * 8;
  const int fr = lane & 15;
  const int fo = (lane >> 4) * 8;

  for (int kb = 0; kb < 24; ++kb) {
    const int k0 = kb * 32;
    const size_t ia0 = (size_t)(m0 + r0) * HD + k0 + k40;
    const size_t ia1 = (size_t)(m0 + r1) * HD + k0 + k41;
    const size_t iw0 = (size_t)(n0 + r0) * HD + k0 + k40;
    const size_t iw1 = (size_t)(n0 + r1) * HD + k0 + k41;
    if (a_bf) {
      gld_lds16((const bf16*)A + ia0, As + c0 * 8);
      gld_lds16((const bf16*)A + ia1, As + c1 * 8);
    } else {
      const float* Af = (const float*)A;
      f32x4 u0 = *(const f32x4*)(Af + ia0), u1 = *(const f32x4*)(Af + ia0 + 4);
      f32x4 u2 = *(const f32x4*)(Af + ia1), u3 = *(const f32x4*)(Af + ia1 + 4);
      bf16x8 v0, v1;
#pragma unroll
      for (int e = 0; e < 4; ++e) { v0[e] = (bf16)u0[e]; v0[e + 4] = (bf16)u1[e];
                                    v1[e] = (bf16)u2[e]; v1[e + 4] = (bf16)u3[e]; }
      *(bf16x8*)(As + c0 * 8) = v0;
      *(bf16x8*)(As + c1 * 8) = v1;
    }
    if (f) {
      gld_lds16((const bf16*)W + iw0, Bs + c0 * 8);
      gld_lds16((const bf16*)W + iw1, Bs + c1 * 8);
    } else {
      const float* Wf = (const float*)W;
      f32x4 u0 = *(const f32x4*)(Wf + iw0), u1 = *(const f32x4*)(Wf + iw0 + 4);
      f32x4 u2 = *(const f32x4*)(Wf + iw1), u3 = *(const f32x4*)(Wf + iw1 + 4);
      bf16x8 v0, v1;
#pragma unroll
      for (int e = 0; e < 4; ++e) { v0[e] = (bf16)u0[e]; v0[e + 4] = (bf16)u1[e];
                                    v1[e] = (bf16)u2[e]; v1[e + 4] = (bf16)u3[e]; }
      *(bf16x8*)(Bs + c0 * 8) = v0;
      *(bf16x8*)(Bs + c1 * 8) = v1;
    }
    __syncthreads();
    bf16x8 af[4], bfr[4];
#pragma unroll
    for (int mi = 0; mi < 4; ++mi)
      af[mi] = *(const bf16x8*)(As + (wm + mi * 16 + fr) * 32 + fo);
#pragma unroll
    for (int ni = 0; ni < 4; ++ni)
      bfr[ni] = *(const bf16x8*)(Bs + (wn + ni * 16 + fr) * 32 + fo);
#pragma unroll
    for (int mi = 0; mi < 4; ++mi)
#pragma unroll
      for (int ni = 0; ni < 4; ++ni)
        acc[mi][ni] = __builtin_amdgcn_mfma_f32_16x16x32_bf16(af[mi], bfr[ni], acc[mi][ni], 0, 0, 0);
    __syncthreads();
  }

  const int rq = (lane >> 4) * 4;
#pragma unroll
  for (int ni = 0; ni < 4; ++ni) {
    const int col = n0 + wn + ni * 16 + fr;
    const float bv = (f ? (float)((const bf16*)args.bias[g])[col]
                        : ((const float*)args.bias[g])[col]) * bscale;
#pragma unroll
    for (int mi = 0; mi < 4; ++mi) {
      const int row = m0 + wm + mi * 16 + rq;
#pragma unroll
      for (int r = 0; r < 4; ++r) {
        const float val = acc[mi][ni][r] + bv;
        if (c_bf) Cb[(size_t)(row + r) * HD + col] = (bf16)val;
        else      Cf[(size_t)(row + r) * HD + col] = val;
      }
    }
  }
}

__global__ __launch_bounds__(256) void attn_mba(
    const bf16* __restrict__ Q, const bf16* __restrict__ Kx, const bf16* __restrict__ Vx,
    const bf16* __restrict__ Qd, const bf16* __restrict__ Kd, const bf16* __restrict__ Vd,
    const void* w11, const void* w12, const void* w21, const void* w22,
    bf16* ctxX, bf16* ctxY, const int* flag) {
  const int qb = blockIdx.x;
  const int bh = blockIdx.y;
  const int z = blockIdx.z;
  const int b = bh / 12, h = bh - b * 12;
  const int f = *flag;

  const bf16* Qp = z ? Qd : Q;
  const bf16* Kp0 = z ? Kd : Kx;
  const bf16* Vp0 = z ? Vd : Vx;
  const bf16* Kp1 = z ? Kx : Kd;
  const bf16* Vp1 = z ? Vx : Vd;
  const float wgt0 = z ? rdscalar(w21, f) : rdscalar(w11, f);
  const float wgt1 = z ? rdscalar(w22, f) : rdscalar(w12, f);
  bf16* Out = z ? ctxY : ctxX;

  const size_t tok0 = (size_t)b * 1024;
  const int fcol = h * 64;
  const int q0 = qb * 64;

  __shared__ __attribute__((aligned(16))) bf16 Qs[64 * 72];
  __shared__ __attribute__((aligned(16))) bf16 Ksh[64 * 72];
  __shared__ __attribute__((aligned(16))) bf16 Vts[64 * 72];
  __shared__ __attribute__((aligned(16))) bf16 Ps[64 * 72];
  __shared__ __attribute__((aligned(16))) float Ss[64 * 65];
  __shared__ float arow[64], lrow[64];

  const int t = threadIdx.x, lane = t & 63, w = t >> 6;
  const int l15 = lane & 15, l4 = lane >> 4;

#pragma unroll
  for (int i = 0; i < 2; ++i) {
    int c = t + i * 256;
    int r = c >> 3, dc = (c & 7) * 8;
    *(bf16x8*)(Qs + r * 72 + dc) = *(const bf16x8*)(Qp + (tok0 + q0 + r) * HD + fcol + dc);
  }

  f32x4 mix[4] = {};

  for (int p = 0; p < 2; ++p) {
    const bf16* Kc = p ? Kp1 : Kp0;
    const bf16* Vc = p ? Vp1 : Vp0;
    const float wg = p ? wgt1 : wgt0;
    float m_r = -INFINITY, l_r = 0.0f;
    f32x4 oacc[4] = {};

    for (int kt = 0; kt < 16; ++kt) {
      __syncthreads();
#pragma unroll
      for (int i = 0; i < 2; ++i) {
        int c = t + i * 256;
        int r = c >> 3, dc = (c & 7) * 8;
        *(bf16x8*)(Ksh + r * 72 + dc) = *(const bf16x8*)(Kc + (tok0 + kt * 64 + r) * HD + fcol + dc);
      }
#pragma unroll
      for (int i = 0; i < 2; ++i) {
        int c = t + i * 256;
        int j = c & 63, dc = c >> 6;
        bf16x8 v = *(const bf16x8*)(Vc + (tok0 + kt * 64 + j) * HD + fcol + dc * 8);
#pragma unroll
        for (int e = 0; e < 8; ++e) Vts[(dc * 8 + e) * 72 + j] = v[e];
      }
      __syncthreads();

      f32x4 sacc[4] = {};
      bf16x8 kf0 = *(const bf16x8*)(Ksh + (w * 16 + l15) * 72 + l4 * 8);
      bf16x8 kf1 = *(const bf16x8*)(Ksh + (w * 16 + l15) * 72 + 32 + l4 * 8);
#pragma unroll
      for (int mi = 0; mi < 4; ++mi) {
        bf16x8 qf0 = *(const bf16x8*)(Qs + (mi * 16 + l15) * 72 + l4 * 8);
        bf16x8 qf1 = *(const bf16x8*)(Qs + (mi * 16 + l15) * 72 + 32 + l4 * 8);
        sacc[mi] = __builtin_amdgcn_mfma_f32_16x16x32_bf16(qf0, kf0, sacc[mi], 0, 0, 0);
        sacc[mi] = __builtin_amdgcn_mfma_f32_16x16x32_bf16(qf1, kf1, sacc[mi], 0, 0, 0);
      }
#pragma unroll
      for (int mi = 0; mi < 4; ++mi)
#pragma unroll
        for (int r = 0; r < 4; ++r)
          Ss[(mi * 16 + l4 * 4 + r) * 65 + w * 16 + l15] =
              fminf(fmaxf(sacc[mi][r] * 0.125f, -3.0e4f), 3.0e4f);
      __syncthreads();

      {
        const int row = w * 16 + l15, seg = l4;
        float sv[16], mx = -INFINITY;
#pragma unroll
        for (int j = 0; j < 16; ++j) { sv[j] = Ss[row * 65 + seg * 16 + j]; mx = fmaxf(mx, sv[j]); }
        mx = fmaxf(mx, __shfl_xor(mx, 16));
        mx = fmaxf(mx, __shfl_xor(mx, 32));
        const float mnew = fmaxf(m_r, mx);
        const float alpha = __expf(m_r - mnew);
        float sum = 0.f;
        bf16x8 p0, p1;
#pragma unroll
        for (int j = 0; j < 8; ++j) { float pv = __expf(sv[j] - mnew); sum += pv; p0[j] = (bf16)pv; }
#pragma unroll
        for (int j = 0; j < 8; ++j) { float pv = __expf(sv[j + 8] - mnew); sum += pv; p1[j] = (bf16)pv; }
        *(bf16x8*)(Ps + row * 72 + seg * 16) = p0;
        *(bf16x8*)(Ps + row * 72 + seg * 16 + 8) = p1;
        sum += __shfl_xor(sum, 16);
        sum += __shfl_xor(sum, 32);
        l_r = l_r * alpha + sum;
        m_r = mnew;
        if (seg == 0) arow[row] = alpha;
      }
      __syncthreads();

      bf16x8 vf0 = *(const bf16x8*)(Vts + (w * 16 + l15) * 72 + l4 * 8);
      bf16x8 vf1 = *(const bf16x8*)(Vts + (w * 16 + l15) * 72 + 32 + l4 * 8);
#pragma unroll
      for (int mi = 0; mi < 4; ++mi) {
        f32x4 a4;
#pragma unroll
        for (int r = 0; r < 4; ++r) a4[r] = arow[mi * 16 + l4 * 4 + r];
        oacc[mi] *= a4;
        bf16x8 pf0 = *(const bf16x8*)(Ps + (mi * 16 + l15) * 72 + l4 * 8);
        bf16x8 pf1 = *(const bf16x8*)(Ps + (mi * 16 + l15) * 72 + 32 + l4 * 8);
        oacc[mi] = __builtin_amdgcn_mfma_f32_16x16x32_bf16(pf0, vf0, oacc[mi], 0, 0, 0);
        oacc[mi] = __builtin_amdgcn_mfma_f32_16x16x32_bf16(pf1, vf1, oacc[mi], 0, 0, 0);
      }
    }

    if (l4 == 0) lrow[w * 16 + l15] = l_r;
    __syncthreads();
#pragma unroll
    for (int mi = 0; mi < 4; ++mi)
#pragma unroll
      for (int r = 0; r < 4; ++r)
        mix[mi][r] += wg * oacc[mi][r] * (1.0f / fmaxf(lrow[mi * 16 + l4 * 4 + r], 1e-30f));
  }

#pragma unroll
  for (int mi = 0; mi < 4; ++mi) {
    const int rowb = q0 + mi * 16 + l4 * 4;
#pragma unroll
    for (int r = 0; r < 4; ++r)
      Out[(tok0 + rowb + r) * HD + fcol + w * 16 + l15] = (bf16)mix[mi][r];
  }
}

extern "C" void kernel_launch(void* const* d_in, const int* in_sizes, int n_in,
                              void* d_out, int out_size, void* d_ws, size_t ws_size,
                              hipStream_t stream) {
  (void)in_sizes; (void)n_in; (void)out_size; (void)ws_size;
  const void* x = d_in[0];
  const void* y = d_in[1];

  bf16* ws = (bf16*)d_ws;
  bf16* Qb = ws + 0ull * ELTS;
  bf16* Kb = ws + 1ull * ELTS;
  bf16* Vb = ws + 2ull * ELTS;
  bf16* Qdb = ws + 3ull * ELTS;
  bf16* Kdb = ws + 4ull * ELTS;
  bf16* Vdb = ws + 5ull * ELTS;
  bf16* ctxX = Qb;    // alias: safe (block-local read-then-write, disjoint slices)
  bf16* ctxY = Qdb;
  int* flag = (int*)(ws + 6ull * ELTS);

  probe_dtype<<<dim3(1), dim3(64), 0, stream>>>((const unsigned int*)x, flag);

  GemmArgs gq;
  {
    const void* A6[6] = {x, x, x, y, y, y};
    const void* W6[6] = {d_in[2], d_in[4], d_in[6], d_in[10], d_in[12], d_in[14]};
    const void* B6[6] = {d_in[3], d_in[5], d_in[7], d_in[11], d_in[13], d_in[15]};
    bf16* C6[6] = {Qb, Kb, Vb, Qdb, Kdb, Vdb};
    for (int i = 0; i < 6; ++i) {
      gq.A[i] = A6[i]; gq.W[i] = W6[i]; gq.bias[i] = B6[i];
      gq.s0[i] = nullptr; gq.s1[i] = nullptr; gq.C[i] = C6[i];
      gq.a_fixed[i] = 0; gq.c_fixed[i] = 1; gq.out_elem_off[i] = 0;
    }
    gq.flag = flag;
  }
  gemm_bt<<<dim3(64, 6, 6), dim3(256), 0, stream>>>(gq);

  attn_mba<<<dim3(16, 96, 2), dim3(256), 0, stream>>>(
      Qb, Kb, Vb, Qdb, Kdb, Vdb, d_in[18], d_in[19], d_in[20], d_in[21],
      ctxX, ctxY, flag);

  GemmArgs gp;
  for (int i = 0; i < 6; ++i) {
    gp.A[i] = ctxX; gp.W[i] = d_in[8]; gp.bias[i] = d_in[9];
    gp.s0[i] = d_in[18]; gp.s1[i] = d_in[19]; gp.C[i] = d_out;
    gp.a_fixed[i] = 1; gp.c_fixed[i] = 0; gp.out_elem_off[i] = 0;
  }
  gp.A[1] = ctxY; gp.W[1] = d_in[16]; gp.bias[1] = d_in[17];
  gp.s0[1] = d_in[20]; gp.s1[1] = d_in[21];
  gp.out_elem_off[1] = (long long)ELTS;   // dtype-aware element offset
  gp.flag = flag;
  gemm_bt<<<dim3(64, 6, 2), dim3(256), 0, stream>>>(gp);
}

// Round 4
// 585.269 us; speedup vs baseline: 1.2339x; 1.2339x over previous
//
#include <hip/hip_runtime.h>

typedef __bf16 bf16;
typedef __bf16 bf16x8 __attribute__((ext_vector_type(8)));
typedef float f32x4 __attribute__((ext_vector_type(4)));

#define HD 768
#define ELTS 6291456   // 8*1024*768

__device__ __forceinline__ void gld_lds16(const bf16* g, bf16* l) {
  __builtin_amdgcn_global_load_lds((const __attribute__((address_space(1))) void*)g,
                                   (__attribute__((address_space(3))) void*)l, 16, 0, 0);
}

__device__ __forceinline__ float rdscalar(const void* p, int f) {
  return f ? (float)((const bf16*)p)[0] : ((const float*)p)[0];
}

__global__ void probe_dtype(const unsigned int* __restrict__ x, int* flag) {
  const int t = threadIdx.x;  // 64 threads
  int bad = 0;
#pragma unroll
  for (int i = 0; i < 4; ++i) {
    unsigned int wd = x[t * 4 + i];
    unsigned int e0 = (wd >> 7) & 0xFF;
    unsigned int e1 = (wd >> 23) & 0xFF;
    bad += (e0 >= 134) + (e1 >= 134);
  }
  unsigned long long m = __ballot(bad > 0);
  if (t == 0) *flag = (m == 0ULL) ? 1 : 0;   // 1 = bf16 inputs
}

struct GemmArgs {
  const void* A[6];
  const void* W[6];
  const void* bias[6];
  const void* s0[6];
  const void* s1[6];
  void* C[6];
  int a_fixed[6];   // 1: A always internal bf16
  int c_fixed[6];   // 1: C always internal bf16; 0: C dtype follows flag
  int vt[6];        // 1: write C transposed per-head: [b][h][d=64][s=1024]
  long long out_elem_off[6];
  const int* flag;
};

__global__ __launch_bounds__(256) void gemm_bt(GemmArgs args) {
  const int g = blockIdx.z;
  const int f = *args.flag;
  const bool a_bf = args.a_fixed[g] || f;
  const bool c_bf = args.c_fixed[g] || f;
  const void* __restrict__ A = args.A[g];
  const void* __restrict__ W = args.W[g];
  bf16* Cb = (bf16*)args.C[g] + args.out_elem_off[g];
  float* Cf = (float*)args.C[g] + args.out_elem_off[g];
  float bscale = 1.0f;
  if (args.s0[g]) bscale = rdscalar(args.s0[g], f) + rdscalar(args.s1[g], f);

  const int m0 = blockIdx.x * 128;
  const int n0 = blockIdx.y * 128;
  const int t = threadIdx.x;
  const int lane = t & 63;
  const int w = t >> 6;
  const int wm = (w >> 1) * 64, wn = (w & 1) * 64;

  __shared__ __attribute__((aligned(16))) bf16 As[128 * 32];
  __shared__ __attribute__((aligned(16))) bf16 Bs[128 * 32];

  f32x4 acc[4][4] = {};

  const int c0 = t, c1 = t + 256;
  const int r0 = c0 >> 2, k40 = (c0 & 3) * 8;
  const int r1 = c1 >> 2, k41 = (c1 & 3) * 8;
  const int fr = lane & 15;
  const int fo = (lane >> 4) * 8;

  for (int kb = 0; kb < 24; ++kb) {
    const int k0 = kb * 32;
    const size_t ia0 = (size_t)(m0 + r0) * HD + k0 + k40;
    const size_t ia1 = (size_t)(m0 + r1) * HD + k0 + k41;
    const size_t iw0 = (size_t)(n0 + r0) * HD + k0 + k40;
    const size_t iw1 = (size_t)(n0 + r1) * HD + k0 + k41;
    if (a_bf) {
      gld_lds16((const bf16*)A + ia0, As + c0 * 8);
      gld_lds16((const bf16*)A + ia1, As + c1 * 8);
    } else {
      const float* Af = (const float*)A;
      f32x4 u0 = *(const f32x4*)(Af + ia0), u1 = *(const f32x4*)(Af + ia0 + 4);
      f32x4 u2 = *(const f32x4*)(Af + ia1), u3 = *(const f32x4*)(Af + ia1 + 4);
      bf16x8 v0, v1;
#pragma unroll
      for (int e = 0; e < 4; ++e) { v0[e] = (bf16)u0[e]; v0[e + 4] = (bf16)u1[e];
                                    v1[e] = (bf16)u2[e]; v1[e + 4] = (bf16)u3[e]; }
      *(bf16x8*)(As + c0 * 8) = v0;
      *(bf16x8*)(As + c1 * 8) = v1;
    }
    if (f) {
      gld_lds16((const bf16*)W + iw0, Bs + c0 * 8);
      gld_lds16((const bf16*)W + iw1, Bs + c1 * 8);
    } else {
      const float* Wf = (const float*)W;
      f32x4 u0 = *(const f32x4*)(Wf + iw0), u1 = *(const f32x4*)(Wf + iw0 + 4);
      f32x4 u2 = *(const f32x4*)(Wf + iw1), u3 = *(const f32x4*)(Wf + iw1 + 4);
      bf16x8 v0, v1;
#pragma unroll
      for (int e = 0; e < 4; ++e) { v0[e] = (bf16)u0[e]; v0[e + 4] = (bf16)u1[e];
                                    v1[e] = (bf16)u2[e]; v1[e + 4] = (bf16)u3[e]; }
      *(bf16x8*)(Bs + c0 * 8) = v0;
      *(bf16x8*)(Bs + c1 * 8) = v1;
    }
    __syncthreads();
    bf16x8 af[4], bfr[4];
#pragma unroll
    for (int mi = 0; mi < 4; ++mi)
      af[mi] = *(const bf16x8*)(As + (wm + mi * 16 + fr) * 32 + fo);
#pragma unroll
    for (int ni = 0; ni < 4; ++ni)
      bfr[ni] = *(const bf16x8*)(Bs + (wn + ni * 16 + fr) * 32 + fo);
#pragma unroll
    for (int mi = 0; mi < 4; ++mi)
#pragma unroll
      for (int ni = 0; ni < 4; ++ni)
        acc[mi][ni] = __builtin_amdgcn_mfma_f32_16x16x32_bf16(af[mi], bfr[ni], acc[mi][ni], 0, 0, 0);
    __syncthreads();
  }

  const int rq = (lane >> 4) * 4;
  const int is_vt = args.vt[g];
#pragma unroll
  for (int ni = 0; ni < 4; ++ni) {
    const int col = n0 + wn + ni * 16 + fr;
    const float bv = (f ? (float)((const bf16*)args.bias[g])[col]
                        : ((const float*)args.bias[g])[col]) * bscale;
#pragma unroll
    for (int mi = 0; mi < 4; ++mi) {
      const int row = m0 + wm + mi * 16 + rq;
#pragma unroll
      for (int r = 0; r < 4; ++r) {
        const float val = acc[mi][ni][r] + bv;
        if (is_vt) {
          const int tok = row + r;
          const int bb = tok >> 10, s = tok & 1023;
          const int hh = col >> 6, d = col & 63;
          Cb[((size_t)(bb * 12 + hh) << 16) + (d << 10) + s] = (bf16)val;
        } else if (c_bf) {
          Cb[(size_t)(row + r) * HD + col] = (bf16)val;
        } else {
          Cf[(size_t)(row + r) * HD + col] = val;
        }
      }
    }
  }
}

// One block per (stream z, batch*head, 64-query tile). Computes S^T = K Q^T so
// softmax runs along registers (lane = one query column); P^T never touches
// LDS (cross-lane shuffles build the PV B-fragment); O accumulates transposed
// in registers. K / V^T / Q staged via async global_load_lds into XOR-swizzled
// unpadded 64x64 tiles (swizzle folded into global address). 2 barriers/kt.
// ctxX aliases Q, ctxY aliases Qd (block-local read-then-write, disjoint slices).
__global__ __launch_bounds__(256, 4) void attn_mba(
    const bf16* __restrict__ Q, const bf16* __restrict__ Kx, const bf16* __restrict__ Vtx,
    const bf16* __restrict__ Qd, const bf16* __restrict__ Kd, const bf16* __restrict__ Vtd,
    const void* w11, const void* w12, const void* w21, const void* w22,
    bf16* ctxX, bf16* ctxY, const int* flag) {
  const int qb = blockIdx.x;   // 0..15
  const int bh = blockIdx.y;   // 0..95  ( == b*12 + h )
  const int z = blockIdx.z;    // 0..1
  const int b = bh / 12;
  const int f = *flag;

  const bf16* Qp  = z ? Qd  : Q;
  const bf16* Kc0 = z ? Kd  : Kx;
  const bf16* Vc0 = z ? Vtd : Vtx;
  const bf16* Kc1 = z ? Kx  : Kd;
  const bf16* Vc1 = z ? Vtx : Vtd;
  const float wgt0 = z ? rdscalar(w21, f) : rdscalar(w11, f);
  const float wgt1 = z ? rdscalar(w22, f) : rdscalar(w12, f);
  bf16* Out = z ? ctxY : ctxX;

  const size_t tok0 = (size_t)b * 1024;
  const size_t vbase = (size_t)bh * 65536;   // [bh][64][1024]
  const int fcol = (bh - b * 12) * 64;
  const int q0 = qb * 64;

  __shared__ __attribute__((aligned(16))) bf16 smem[12288];
  bf16* Ks = smem;            // 64x64 keys x d   (swizzled)
  bf16* Vs = smem + 4096;     // 64x64 d x keys   (swizzled)
  bf16* Qs = smem + 8192;     // 64x64 query x d  (swizzled)

  const int t = threadIdx.x, lane = t & 63, w = t >> 6;
  const int l15 = lane & 15, l4 = lane >> 4;

  // stage Q tile once (async, swizzled)
#pragma unroll
  for (int i = 0; i < 2; ++i) {
    const int q = t + i * 256;
    const int row = q >> 3, slot = q & 7;
    gld_lds16(Qp + (tok0 + q0 + row) * HD + fcol + ((slot ^ (row & 7)) << 3), Qs + q * 8);
  }

  const int qrow = w * 16 + l15;            // this wave's query rows
  const int qs0 = ((0 + l4) ^ (qrow & 7)) << 3;
  const int qs1 = ((4 + l4) ^ (qrow & 7)) << 3;

  f32x4 mixT[4] = {};

  for (int p = 0; p < 2; ++p) {
    const bf16* Kc = p ? Kc1 : Kc0;
    const bf16* Vc = p ? Vc1 : Vc0;
    const float wg = p ? wgt1 : wgt0;
    float m_r = -INFINITY, l_r = 0.0f;
    f32x4 oaccT[4] = {};

    for (int kt = 0; kt < 16; ++kt) {
      __syncthreads();   // prior readers of Ks/Vs done
#pragma unroll
      for (int i = 0; i < 2; ++i) {
        const int q = t + i * 256;
        const int row = q >> 3, slot = q & 7;
        const int gs = (slot ^ (row & 7)) << 3;
        gld_lds16(Kc + (tok0 + kt * 64 + row) * HD + fcol + gs, Ks + q * 8);
        gld_lds16(Vc + vbase + (size_t)row * 1024 + kt * 64 + gs, Vs + q * 8);
      }
      __syncthreads();   // staging complete (drains vmcnt)

      // S^T = K Q^T : D[key][query], wave w owns queries w*16..+15
      bf16x8 qf0 = *(const bf16x8*)(Qs + qrow * 64 + qs0);
      bf16x8 qf1 = *(const bf16x8*)(Qs + qrow * 64 + qs1);
      float sv[4][4];
      float mx = -INFINITY;
#pragma unroll
      for (int mi = 0; mi < 4; ++mi) {
        const int kr = mi * 16 + l15;
        bf16x8 kf0 = *(const bf16x8*)(Ks + kr * 64 + (((0 + l4) ^ (kr & 7)) << 3));
        bf16x8 kf1 = *(const bf16x8*)(Ks + kr * 64 + (((4 + l4) ^ (kr & 7)) << 3));
        f32x4 s = {};
        s = __builtin_amdgcn_mfma_f32_16x16x32_bf16(kf0, qf0, s, 0, 0, 0);
        s = __builtin_amdgcn_mfma_f32_16x16x32_bf16(kf1, qf1, s, 0, 0, 0);
#pragma unroll
        for (int r = 0; r < 4; ++r) {
          sv[mi][r] = s[r] * 0.125f;
          mx = fmaxf(mx, sv[mi][r]);
        }
      }
      // full 64-key max per query (cross-l4 lanes)
      mx = fmaxf(mx, __shfl_xor(mx, 16));
      mx = fmaxf(mx, __shfl_xor(mx, 32));
      const float mnew = fmaxf(m_r, mx);
      const float alpha = __expf(m_r - mnew);
      float pv[4][4];
      float sum = 0.0f;
#pragma unroll
      for (int mi = 0; mi < 4; ++mi)
#pragma unroll
        for (int r = 0; r < 4; ++r) {
          pv[mi][r] = __expf(sv[mi][r] - mnew);
          sum += pv[mi][r];
        }
      sum += __shfl_xor(sum, 16);
      sum += __shfl_xor(sum, 32);
      l_r = l_r * alpha + sum;
      m_r = mnew;
#pragma unroll
      for (int mi = 0; mi < 4; ++mi) oaccT[mi] *= alpha;

      // PV: O^T += V^T P^T. Build P^T B-frag (keys k, queries n=l15) via shuffles.
#pragma unroll
      for (int c = 0; c < 2; ++c) {
        bf16x8 pf;
#pragma unroll
        for (int j = 0; j < 8; ++j) {
          const int src = ((j >> 2) + 2 * (l4 & 1)) * 16 + l15;
          const float v0 = __shfl(pv[2 * c][j & 3], src, 64);
          const float v1 = __shfl(pv[2 * c + 1][j & 3], src, 64);
          pf[j] = (bf16)((l4 >> 1) ? v1 : v0);
        }
#pragma unroll
        for (int mi = 0; mi < 4; ++mi) {
          const int vr = mi * 16 + l15;
          bf16x8 vf = *(const bf16x8*)(Vs + vr * 64 + ((((c << 2) + l4) ^ (vr & 7)) << 3));
          oaccT[mi] = __builtin_amdgcn_mfma_f32_16x16x32_bf16(vf, pf, oaccT[mi], 0, 0, 0);
        }
      }
    }

    const float sc = wg / l_r;
#pragma unroll
    for (int mi = 0; mi < 4; ++mi)
#pragma unroll
      for (int r = 0; r < 4; ++r)
        mixT[mi][r] += sc * oaccT[mi][r];
  }

  // epilogue: transpose O^T -> O through LDS, coalesced b128 store
  __syncthreads();
  bf16* T = smem;   // 64 x 72 = 4608 elems, fits
#pragma unroll
  for (int mi = 0; mi < 4; ++mi)
#pragma unroll
    for (int r = 0; r < 4; ++r)
      T[qrow * 72 + mi * 16 + l4 * 4 + r] = (bf16)mixT[mi][r];
  __syncthreads();
#pragma unroll
  for (int i = 0; i < 2; ++i) {
    const int q = t + i * 256;
    const int row = q >> 3, dc = (q & 7) * 8;
    *(bf16x8*)(Out + (tok0 + q0 + row) * HD + fcol + dc) = *(const bf16x8*)(T + row * 72 + dc);
  }
}

extern "C" void kernel_launch(void* const* d_in, const int* in_sizes, int n_in,
                              void* d_out, int out_size, void* d_ws, size_t ws_size,
                              hipStream_t stream) {
  (void)in_sizes; (void)n_in; (void)out_size; (void)ws_size;
  const void* x = d_in[0];
  const void* y = d_in[1];

  bf16* ws = (bf16*)d_ws;
  bf16* Qb  = ws + 0ull * ELTS;
  bf16* Kb  = ws + 1ull * ELTS;
  bf16* Vtb = ws + 2ull * ELTS;   // [b][h][d][s]
  bf16* Qdb = ws + 3ull * ELTS;
  bf16* Kdb = ws + 4ull * ELTS;
  bf16* Vtdb = ws + 5ull * ELTS;
  bf16* ctxX = Qb;    // alias: safe (block-local read-then-write, disjoint slices)
  bf16* ctxY = Qdb;
  int* flag = (int*)(ws + 6ull * ELTS);

  probe_dtype<<<dim3(1), dim3(64), 0, stream>>>((const unsigned int*)x, flag);

  GemmArgs gq;
  {
    const void* A6[6] = {x, x, x, y, y, y};
    const void* W6[6] = {d_in[2], d_in[4], d_in[6], d_in[10], d_in[12], d_in[14]};
    const void* B6[6] = {d_in[3], d_in[5], d_in[7], d_in[11], d_in[13], d_in[15]};
    bf16* C6[6] = {Qb, Kb, Vtb, Qdb, Kdb, Vtdb};
    for (int i = 0; i < 6; ++i) {
      gq.A[i] = A6[i]; gq.W[i] = W6[i]; gq.bias[i] = B6[i];
      gq.s0[i] = nullptr; gq.s1[i] = nullptr; gq.C[i] = C6[i];
      gq.a_fixed[i] = 0; gq.c_fixed[i] = 1; gq.out_elem_off[i] = 0;
      gq.vt[i] = (i == 2 || i == 5) ? 1 : 0;
    }
    gq.flag = flag;
  }
  gemm_bt<<<dim3(64, 6, 6), dim3(256), 0, stream>>>(gq);

  attn_mba<<<dim3(16, 96, 2), dim3(256), 0, stream>>>(
      Qb, Kb, Vtb, Qdb, Kdb, Vtdb, d_in[18], d_in[19], d_in[20], d_in[21],
      ctxX, ctxY, flag);

  GemmArgs gp;
  for (int i = 0; i < 6; ++i) {
    gp.A[i] = ctxX; gp.W[i] = d_in[8]; gp.bias[i] = d_in[9];
    gp.s0[i] = d_in[18]; gp.s1[i] = d_in[19]; gp.C[i] = d_out;
    gp.a_fixed[i] = 1; gp.c_fixed[i] = 0; gp.vt[i] = 0; gp.out_elem_off[i] = 0;
  }
  gp.A[1] = ctxY; gp.W[1] = d_in[16]; gp.bias[1] = d_in[17];
  gp.s0[1] = d_in[20]; gp.s1[1] = d_in[21];
  gp.out_elem_off[1] = (long long)ELTS;
  gp.flag = flag;
  gemm_bt<<<dim3(64, 6, 2), dim3(256), 0, stream>>>(gp);
}

// Round 6
// 466.592 us; speedup vs baseline: 1.5478x; 1.2543x over previous
//
#include <hip/hip_runtime.h>

typedef __bf16 bf16;
typedef __bf16 bf16x8 __attribute__((ext_vector_type(8)));
typedef float f32x4 __attribute__((ext_vector_type(4)));

#define HD 768
#define ELTS 6291456   // 8*1024*768
#define WELTS 589824   // 768*768

__device__ __forceinline__ void gld_lds16(const bf16* g, bf16* l) {
  __builtin_amdgcn_global_load_lds((const __attribute__((address_space(1))) void*)g,
                                   (__attribute__((address_space(3))) void*)l, 16, 0, 0);
}

__device__ __forceinline__ float rdscalar(const void* p, int f) {
  return f ? (float)((const bf16*)p)[0] : ((const float*)p)[0];
}

__global__ void probe_dtype(const unsigned int* __restrict__ x, int* flag) {
  const int t = threadIdx.x;  // 64 threads
  int bad = 0;
#pragma unroll
  for (int i = 0; i < 4; ++i) {
    unsigned int wd = x[t * 4 + i];
    unsigned int e0 = (wd >> 7) & 0xFF;
    unsigned int e1 = (wd >> 23) & 0xFF;
    bad += (e0 >= 134) + (e1 >= 134);
  }
  unsigned long long m = __ballot(bad > 0);
  if (t == 0) *flag = (m == 0ULL) ? 1 : 0;   // 1 = bf16 inputs
}

// fp32 -> bf16 conversion of x, y, and the 6 QKV weights/biases (flag==0 only).
// Destinations live in d_out and are consumed ONLY by the QKV GEMM, which is
// stream-ordered before the projection GEMM writes d_out.
struct CvtArgs {
  const float* src[16];
  bf16* dst[16];
  int n[16];
  const int* flag;
};
__global__ __launch_bounds__(256) void convert_inputs(CvtArgs a) {
  if (*a.flag) return;
  const int seg = blockIdx.y;
  const float* s = a.src[seg];
  bf16* d = a.dst[seg];
  const int n4 = a.n[seg] >> 2;
  for (int i = blockIdx.x * blockDim.x + threadIdx.x; i < n4; i += gridDim.x * blockDim.x) {
    f32x4 v = *(const f32x4*)(s + i * 4);
    bf16 o[4];
#pragma unroll
    for (int e = 0; e < 4; ++e) o[e] = (bf16)v[e];
    *(unsigned long long*)(d + i * 4) = *(unsigned long long*)o;
  }
}

struct GemmArgs {
  const void* A[6];     // bf16 when flag==1
  const void* Ac[6];    // bf16 when flag==0 (converted / internal)
  const void* W[6];     // bf16 when flag==1
  const void* Wc[6];    // flag==0: bf16 converted (ext_w=0) or fp32 original (ext_w=1)
  const void* bias[6];  // bf16 when flag==1
  const void* biasc[6]; // flag==0: bf16 converted (ext_w=0) or fp32 original (ext_w=1)
  const void* s0[6];
  const void* s1[6];
  void* C[6];
  float cmul[6];        // epilogue scale on (acc + bias)
  int c_fixed[6];       // 1: C always internal bf16; 0: C dtype follows flag
  int vt[6];            // 1: write C transposed per-head: [b][h][d=64][s=1024]
  int ext_w[6];         // 1: when flag==0, W/bias are fp32 -> convert in-kernel
  long long out_elem_off[6];
  const int* flag;
};

// C[M=8192, N=768] = (A[M,768] @ W[N,768]^T + bias*bscale) * cmul
__global__ __launch_bounds__(256) void gemm_bt(GemmArgs args) {
  const int g = blockIdx.z;
  const int f = *args.flag;
  const bool c_bf = args.c_fixed[g] || f;
  const bool w_f32 = (!f) && args.ext_w[g];
  const bf16* __restrict__ A = (const bf16*)(f ? args.A[g] : args.Ac[g]);
  const void* __restrict__ Wp = f ? args.W[g] : args.Wc[g];
  const void* __restrict__ bias = f ? args.bias[g] : args.biasc[g];
  bf16* Cb = (bf16*)args.C[g] + args.out_elem_off[g];
  float* Cf = (float*)args.C[g] + args.out_elem_off[g];
  float bscale = 1.0f;
  if (args.s0[g]) bscale = rdscalar(args.s0[g], f) + rdscalar(args.s1[g], f);
  const float cmul = args.cmul[g];

  const int m0 = blockIdx.x * 128;
  const int n0 = blockIdx.y * 128;
  const int t = threadIdx.x;
  const int lane = t & 63;
  const int w = t >> 6;
  const int wm = (w >> 1) * 64, wn = (w & 1) * 64;

  __shared__ __attribute__((aligned(16))) bf16 As[128 * 32];
  __shared__ __attribute__((aligned(16))) bf16 Bs[128 * 32];

  f32x4 acc[4][4] = {};

  const int c0 = t, c1 = t + 256;
  const int r0 = c0 >> 2, k40 = (c0 & 3) * 8;
  const int r1 = c1 >> 2, k41 = (c1 & 3) * 8;
  const int fr = lane & 15;
  const int fo = (lane >> 4) * 8;

  for (int kb = 0; kb < 24; ++kb) {
    const int k0 = kb * 32;
    gld_lds16(A + (size_t)(m0 + r0) * HD + k0 + k40, As + c0 * 8);
    gld_lds16(A + (size_t)(m0 + r1) * HD + k0 + k41, As + c1 * 8);
    const size_t iw0 = (size_t)(n0 + r0) * HD + k0 + k40;
    const size_t iw1 = (size_t)(n0 + r1) * HD + k0 + k41;
    if (!w_f32) {
      gld_lds16((const bf16*)Wp + iw0, Bs + c0 * 8);
      gld_lds16((const bf16*)Wp + iw1, Bs + c1 * 8);
    } else {
      const float* Wf = (const float*)Wp;
      f32x4 u0 = *(const f32x4*)(Wf + iw0), u1 = *(const f32x4*)(Wf + iw0 + 4);
      f32x4 u2 = *(const f32x4*)(Wf + iw1), u3 = *(const f32x4*)(Wf + iw1 + 4);
      bf16x8 v0, v1;
#pragma unroll
      for (int e = 0; e < 4; ++e) { v0[e] = (bf16)u0[e]; v0[e + 4] = (bf16)u1[e];
                                    v1[e] = (bf16)u2[e]; v1[e + 4] = (bf16)u3[e]; }
      *(bf16x8*)(Bs + c0 * 8) = v0;
      *(bf16x8*)(Bs + c1 * 8) = v1;
    }
    __syncthreads();
    bf16x8 af[4], bfr[4];
#pragma unroll
    for (int mi = 0; mi < 4; ++mi)
      af[mi] = *(const bf16x8*)(As + (wm + mi * 16 + fr) * 32 + fo);
#pragma unroll
    for (int ni = 0; ni < 4; ++ni)
      bfr[ni] = *(const bf16x8*)(Bs + (wn + ni * 16 + fr) * 32 + fo);
#pragma unroll
    for (int mi = 0; mi < 4; ++mi)
#pragma unroll
      for (int ni = 0; ni < 4; ++ni)
        acc[mi][ni] = __builtin_amdgcn_mfma_f32_16x16x32_bf16(af[mi], bfr[ni], acc[mi][ni], 0, 0, 0);
    __syncthreads();
  }

  const int rq = (lane >> 4) * 4;
  const int is_vt = args.vt[g];
#pragma unroll
  for (int ni = 0; ni < 4; ++ni) {
    const int col = n0 + wn + ni * 16 + fr;
    const float bv = (w_f32 ? ((const float*)bias)[col]
                            : (float)((const bf16*)bias)[col]) * bscale;
#pragma unroll
    for (int mi = 0; mi < 4; ++mi) {
      const int row = m0 + wm + mi * 16 + rq;
#pragma unroll
      for (int r = 0; r < 4; ++r) {
        const float val = (acc[mi][ni][r] + bv) * cmul;
        if (is_vt) {
          const int tok = row + r;
          const int bb = tok >> 10, s = tok & 1023;
          const int hh = col >> 6, d = col & 63;
          Cb[((size_t)(bb * 12 + hh) << 16) + (d << 10) + s] = (bf16)val;
        } else if (c_bf) {
          Cb[(size_t)(row + r) * HD + col] = (bf16)val;
        } else {
          Cf[(size_t)(row + r) * HD + col] = val;
        }
      }
    }
  }
}

// One block per (stream z, batch*head, 64-query tile). S^T = K Q^T with K rows
// PERMUTED (pi: bit5->5, bits3:2->4:3, bit4->2, bits1:0->1:0) at staging so the
// C-layout scores are already in PV-B-fragment order (zero cross-lane shuffles).
// Double-buffered K/V staging. Q pre-scaled by 0.125 in its GEMM.
// ctxX aliases Q, ctxY aliases Qd (block-local read-then-write, disjoint slices).
__global__ __launch_bounds__(256, 4) void attn_mba(
    const bf16* __restrict__ Q, const bf16* __restrict__ Kx, const bf16* __restrict__ Vtx,
    const bf16* __restrict__ Qd, const bf16* __restrict__ Kd, const bf16* __restrict__ Vtd,
    const void* w11, const void* w12, const void* w21, const void* w22,
    bf16* ctxX, bf16* ctxY, const int* flag) {
  const int qb = blockIdx.x;   // 0..15
  const int bh = blockIdx.y;   // 0..95
  const int z = blockIdx.z;    // 0..1
  const int b = bh / 12;
  const int f = *flag;

  const bf16* Qp  = z ? Qd  : Q;
  const bf16* Kc0 = z ? Kd  : Kx;
  const bf16* Vc0 = z ? Vtd : Vtx;
  const bf16* Kc1 = z ? Kx  : Kd;
  const bf16* Vc1 = z ? Vtx : Vtd;
  const float wgt0 = z ? rdscalar(w21, f) : rdscalar(w11, f);
  const float wgt1 = z ? rdscalar(w22, f) : rdscalar(w12, f);
  bf16* Out = z ? ctxY : ctxX;

  const size_t tok0 = (size_t)b * 1024;
  const size_t vbase = (size_t)bh * 65536;   // [bh][64][1024]
  const int fcol = (bh - b * 12) * 64;
  const int q0 = qb * 64;

  __shared__ __attribute__((aligned(16))) bf16 smem[20480];  // 40 KB
  bf16* Qs = smem;              // 4096: query x d (swizzled)
  bf16* Ks = smem + 4096;       // 2 x 4096: permuted keys x d (swizzled)
  bf16* Vs = smem + 12288;      // 2 x 4096: d x keys (swizzled)

  const int t = threadIdx.x, lane = t & 63, w = t >> 6;
  const int l15 = lane & 15, l4 = lane >> 4;

  // stage Q tile once (async, swizzled)
#pragma unroll
  for (int i = 0; i < 2; ++i) {
    const int q = t + i * 256;
    const int g = q >> 3, slot = q & 7;
    gld_lds16(Qp + (tok0 + q0 + g) * HD + fcol + ((slot ^ (g & 7)) << 3), Qs + q * 8);
  }

  auto stage = [&](int nit) {
    const bf16* Kc = nit < 16 ? Kc0 : Kc1;
    const bf16* Vc = nit < 16 ? Vc0 : Vc1;
    const int kt = nit & 15;
    bf16* Kb = Ks + (nit & 1) * 4096;
    bf16* Vb = Vs + (nit & 1) * 4096;
#pragma unroll
    for (int i = 0; i < 2; ++i) {
      const int q = t + i * 256;
      const int g = q >> 3, slot = q & 7;
      const int gs = (slot ^ (g & 7)) << 3;
      const int kp = (g & 32) + ((g & 12) << 1) + ((g & 16) >> 2) + (g & 3);
      gld_lds16(Kc + (tok0 + kt * 64 + kp) * HD + fcol + gs, Kb + q * 8);
      gld_lds16(Vc + vbase + (size_t)g * 1024 + kt * 64 + gs, Vb + q * 8);
    }
  };

  stage(0);
  __syncthreads();   // Q + first K/V staged

  const int qrow = w * 16 + l15;
  const bf16x8 qf0 = *(const bf16x8*)(Qs + qrow * 64 + ((l4 ^ (qrow & 7)) << 3));
  const bf16x8 qf1 = *(const bf16x8*)(Qs + qrow * 64 + (((4 + l4) ^ (qrow & 7)) << 3));

  f32x4 mixT[4] = {};
  f32x4 oaccT[4] = {};
  float m_r = -INFINITY, l_r = 0.0f;

  for (int it = 0; it < 32; ++it) {
    if (it) __syncthreads();        // stage(it) landed; prev readers done
    if (it + 1 < 32) stage(it + 1); // prefetch flies across this compute
    const bf16* Kb = Ks + (it & 1) * 4096;
    const bf16* Vb = Vs + (it & 1) * 4096;

    float pv[4][4];
    float mx = -INFINITY;
#pragma unroll
    for (int mi = 0; mi < 4; ++mi) {
      const int kr = mi * 16 + l15;
      bf16x8 kf0 = *(const bf16x8*)(Kb + kr * 64 + ((l4 ^ (kr & 7)) << 3));
      bf16x8 kf1 = *(const bf16x8*)(Kb + kr * 64 + (((4 + l4) ^ (kr & 7)) << 3));
      f32x4 s = {};
      s = __builtin_amdgcn_mfma_f32_16x16x32_bf16(kf0, qf0, s, 0, 0, 0);
      s = __builtin_amdgcn_mfma_f32_16x16x32_bf16(kf1, qf1, s, 0, 0, 0);
#pragma unroll
      for (int r = 0; r < 4; ++r) {
        pv[mi][r] = s[r];
        mx = fmaxf(mx, s[r]);
      }
    }
    mx = fmaxf(mx, __shfl_xor(mx, 16));
    mx = fmaxf(mx, __shfl_xor(mx, 32));
    const float mnew = fmaxf(m_r, mx);
    const float alpha = __expf(m_r - mnew);
    float sum = 0.0f;
#pragma unroll
    for (int mi = 0; mi < 4; ++mi)
#pragma unroll
      for (int r = 0; r < 4; ++r) {
        pv[mi][r] = __expf(pv[mi][r] - mnew);
        sum += pv[mi][r];
      }
    sum += __shfl_xor(sum, 16);
    sum += __shfl_xor(sum, 32);
    l_r = l_r * alpha + sum;
    m_r = mnew;
#pragma unroll
    for (int mi = 0; mi < 4; ++mi) oaccT[mi] *= alpha;

    // PV: O^T += V^T P^T ; P^T B-frag is a pure in-lane repack of pv
#pragma unroll
    for (int c = 0; c < 2; ++c) {
      bf16x8 pf;
#pragma unroll
      for (int j = 0; j < 8; ++j)
        pf[j] = (bf16)pv[2 * c + (j >> 2)][j & 3];
#pragma unroll
      for (int mi = 0; mi < 4; ++mi) {
        const int vr = mi * 16 + l15;
        bf16x8 vf = *(const bf16x8*)(Vb + vr * 64 + ((((c << 2) + l4) ^ (vr & 7)) << 3));
        oaccT[mi] = __builtin_amdgcn_mfma_f32_16x16x32_bf16(vf, pf, oaccT[mi], 0, 0, 0);
      }
    }

    if ((it & 15) == 15) {   // finalize pass
      const float sc = (it < 16 ? wgt0 : wgt1) / l_r;
#pragma unroll
      for (int mi = 0; mi < 4; ++mi) {
#pragma unroll
        for (int r = 0; r < 4; ++r) mixT[mi][r] += sc * oaccT[mi][r];
        oaccT[mi] = f32x4{};
      }
      m_r = -INFINITY; l_r = 0.0f;
    }
  }

  // epilogue: transpose O^T -> O through LDS, coalesced b128 store
  __syncthreads();
  bf16* T = smem;   // 64 x 72
#pragma unroll
  for (int mi = 0; mi < 4; ++mi)
#pragma unroll
    for (int r = 0; r < 4; ++r)
      T[qrow * 72 + mi * 16 + l4 * 4 + r] = (bf16)mixT[mi][r];
  __syncthreads();
#pragma unroll
  for (int i = 0; i < 2; ++i) {
    const int q = t + i * 256;
    const int g = q >> 3, dc = (q & 7) * 8;
    *(bf16x8*)(Out + (tok0 + q0 + g) * HD + fcol + dc) = *(const bf16x8*)(T + g * 72 + dc);
  }
}

extern "C" void kernel_launch(void* const* d_in, const int* in_sizes, int n_in,
                              void* d_out, int out_size, void* d_ws, size_t ws_size,
                              hipStream_t stream) {
  (void)in_sizes; (void)n_in; (void)out_size; (void)ws_size;
  const void* x = d_in[0];
  const void* y = d_in[1];

  bf16* ws = (bf16*)d_ws;
  bf16* Qb   = ws + 0ull * ELTS;
  bf16* Kb   = ws + 1ull * ELTS;
  bf16* Vtb  = ws + 2ull * ELTS;   // [b][h][d][s]
  bf16* Qdb  = ws + 3ull * ELTS;
  bf16* Kdb  = ws + 4ull * ELTS;
  bf16* Vtdb = ws + 5ull * ELTS;
  bf16* ctxX = Qb;    // alias: safe (block-local read-then-write, disjoint slices)
  bf16* ctxY = Qdb;
  int* flag = (int*)(ws + 6ull * ELTS);

  // Conversion scratch in d_out — consumed ONLY by the QKV GEMM (stream-ordered
  // before any d_out write by the projection GEMM). Projection weights are
  // converted in-kernel (ext_w=1), so nothing in d_out is read after attn.
  bf16* cb = (bf16*)d_out;
  bf16* xb = cb;                              // ELTS
  bf16* yb = cb + (size_t)ELTS;               // ELTS
  bf16* Wcv = cb + 2ull * ELTS;               // 6 x WELTS (Wq,Wk,Wv,Wqd,Wkd,Wvd)
  bf16* bcv = Wcv + 6ull * WELTS;             // 6 x 768
  // total: 2*ELTS + 6*WELTS + 6*768 bf16 = 32.3 MB < 50.3 MB fp32 out region

  probe_dtype<<<dim3(1), dim3(64), 0, stream>>>((const unsigned int*)x, flag);

  CvtArgs ca;
  {
    const int wsrc[6] = {2, 4, 6, 10, 12, 14};   // QKV weights only
    ca.src[0] = (const float*)x;  ca.dst[0] = xb;  ca.n[0] = ELTS;
    ca.src[1] = (const float*)y;  ca.dst[1] = yb;  ca.n[1] = ELTS;
    for (int i = 0; i < 6; ++i) {
      ca.src[2 + i] = (const float*)d_in[wsrc[i]];
      ca.dst[2 + i] = Wcv + (size_t)i * WELTS;
      ca.n[2 + i] = WELTS;
      ca.src[8 + i] = (const float*)d_in[wsrc[i] + 1];
      ca.dst[8 + i] = bcv + (size_t)i * 768;
      ca.n[8 + i] = 768;
    }
    ca.flag = flag;
  }
  convert_inputs<<<dim3(512, 14), dim3(256), 0, stream>>>(ca);

  GemmArgs gq;
  {
    const void* A6[6]  = {x, x, x, y, y, y};
    const void* Ac6[6] = {xb, xb, xb, yb, yb, yb};
    const int di[6] = {2, 4, 6, 10, 12, 14};
    bf16* C6[6] = {Qb, Kb, Vtb, Qdb, Kdb, Vtdb};
    for (int i = 0; i < 6; ++i) {
      gq.A[i] = A6[i]; gq.Ac[i] = Ac6[i];
      gq.W[i] = d_in[di[i]]; gq.Wc[i] = Wcv + (size_t)i * WELTS;
      gq.bias[i] = d_in[di[i] + 1]; gq.biasc[i] = bcv + (size_t)i * 768;
      gq.s0[i] = nullptr; gq.s1[i] = nullptr; gq.C[i] = C6[i];
      gq.cmul[i] = (i == 0 || i == 3) ? 0.125f : 1.0f;   // pre-scale Q, Qd
      gq.c_fixed[i] = 1; gq.ext_w[i] = 0; gq.out_elem_off[i] = 0;
      gq.vt[i] = (i == 2 || i == 5) ? 1 : 0;
    }
    gq.flag = flag;
  }
  gemm_bt<<<dim3(64, 6, 6), dim3(256), 0, stream>>>(gq);

  attn_mba<<<dim3(16, 96, 2), dim3(256), 0, stream>>>(
      Qb, Kb, Vtb, Qdb, Kdb, Vtdb, d_in[18], d_in[19], d_in[20], d_in[21],
      ctxX, ctxY, flag);

  GemmArgs gp;
  for (int i = 0; i < 6; ++i) {
    gp.A[i] = ctxX; gp.Ac[i] = ctxX;
    gp.W[i] = d_in[8]; gp.Wc[i] = d_in[8];        // fp32 original when flag==0
    gp.bias[i] = d_in[9]; gp.biasc[i] = d_in[9];  // fp32 original when flag==0
    gp.s0[i] = d_in[18]; gp.s1[i] = d_in[19]; gp.C[i] = d_out;
    gp.cmul[i] = 1.0f; gp.c_fixed[i] = 0; gp.vt[i] = 0;
    gp.ext_w[i] = 1; gp.out_elem_off[i] = 0;
  }
  gp.A[1] = ctxY; gp.Ac[1] = ctxY;
  gp.W[1] = d_in[16]; gp.Wc[1] = d_in[16];
  gp.bias[1] = d_in[17]; gp.biasc[1] = d_in[17];
  gp.s0[1] = d_in[20]; gp.s1[1] = d_in[21];
  gp.out_elem_off[1] = (long long)ELTS;
  gp.flag = flag;
  gemm_bt<<<dim3(64, 6, 2), dim3(256), 0, stream>>>(gp);
}